// Round 1
// baseline (205.122 us; speedup 1.0000x reference)
//
#include <hip/hip_runtime.h>
#include <hip/hip_bf16.h>

// Problem geometry (fixed by the reference):
//   A = hidden_states [8*4096, 768] fp32
//   W = concat(q,k,v weights) [2304, 768] fp32 (nn.Linear: out = x @ W^T + b)
//   C = [32768, 2304] fp32, written as three [32768,768] blocks (q,k,v) into d_out.
#define M_TOT 32768
#define K_TOT 768
#define N_TOT 2304
#define H     768
#define BM 128
#define BN 128
#define BK 64
#define NB_N 18                 // N_TOT / BN
#define OUT_PER 25165824        // M_TOT * H

typedef __attribute__((ext_vector_type(8))) short bf16x8;   // 8 bf16 = 4 VGPRs
typedef __attribute__((ext_vector_type(4))) float f32x4;

__device__ __forceinline__ void gld_lds16(const void* g, void* l) {
    __builtin_amdgcn_global_load_lds(
        (const __attribute__((address_space(1))) unsigned int*)g,
        (__attribute__((address_space(3))) unsigned int*)l,
        16, 0, 0);
}

__device__ __forceinline__ unsigned short f2bf_rne(float f) {
    unsigned u = __builtin_bit_cast(unsigned, f);
    unsigned r = (u + 0x7FFFu + ((u >> 16) & 1u)) >> 16;
    return (unsigned short)r;
}

// ---------------------------------------------------------------------------
// Pass 1: fp32 -> bf16 conversion of A and the three weight matrices into ws,
// plus packing the three biases into one fp32 [2304] array.
// ---------------------------------------------------------------------------
__global__ void convert_pack(const float* __restrict__ A,
                             const float* __restrict__ wq, const float* __restrict__ wk,
                             const float* __restrict__ wv,
                             const float* __restrict__ bq, const float* __restrict__ bk,
                             const float* __restrict__ bv,
                             unsigned short* __restrict__ Ab,
                             unsigned short* __restrict__ Wb,
                             float* __restrict__ biasb) {
    const int NA4 = (M_TOT * K_TOT) / 4;   // 6291456 float4 chunks of A
    const int NW4 = (H * H) / 4;           // 147456 per weight matrix
    const int total = NA4 + 3 * NW4;       // 6733824

    int tid = blockIdx.x * blockDim.x + threadIdx.x;

    if (tid < 2304) {
        biasb[tid] = (tid < 768) ? bq[tid] : (tid < 1536) ? bk[tid - 768] : bv[tid - 1536];
    }

    const int stride = gridDim.x * blockDim.x;
    for (int i = tid; i < total; i += stride) {
        const float* src;
        unsigned short* dst;
        int idx;
        if (i < NA4) {
            src = A; dst = Ab; idx = i;
        } else {
            int j = i - NA4;
            int w = j / NW4;
            idx = j - w * NW4;
            src = (w == 0) ? wq : (w == 1) ? wk : wv;
            dst = Wb + (size_t)w * (H * H);
        }
        float4 v = reinterpret_cast<const float4*>(src)[idx];
        ushort4 o;
        o.x = f2bf_rne(v.x);
        o.y = f2bf_rne(v.y);
        o.z = f2bf_rne(v.z);
        o.w = f2bf_rne(v.w);
        reinterpret_cast<ushort4*>(dst)[idx] = o;
    }
}

// ---------------------------------------------------------------------------
// Pass 2: bf16 MFMA GEMM, m97-structure:
//   128x128 tile, BK=64, 256 threads = 4 waves in 2x2, each wave owns 64x64
//   (4x4 fragments of 16x16), mfma_f32_16x16x32_bf16, global_load_lds w=16,
//   linear LDS (T2 swizzle is measured-null at 128²+2-phase), 2 barriers/K-step.
// ---------------------------------------------------------------------------
__global__ __launch_bounds__(256, 2) void qkv_gemm(
        const unsigned short* __restrict__ Ab,
        const unsigned short* __restrict__ Wb,
        const float* __restrict__ bias,
        float* __restrict__ out) {

    __shared__ __align__(16) unsigned short sA[BM * BK];
    __shared__ __align__(16) unsigned short sB[BN * BK];

    const int tid  = threadIdx.x;
    const int lane = tid & 63;
    const int wid  = tid >> 6;       // 0..3
    const int wr   = wid >> 1;       // wave row 0..1  (owns rows wr*64..+63)
    const int wc   = wid & 1;        // wave col 0..1  (owns cols wc*64..+63)

    const int bid = blockIdx.x;
    const int bm  = bid / NB_N;
    const int bn  = bid - bm * NB_N;
    const int m0  = bm * BM;
    const int n0  = bn * BN;

    f32x4 acc[4][4];
#pragma unroll
    for (int i = 0; i < 4; i++)
#pragma unroll
        for (int j = 0; j < 4; j++)
            acc[i][j] = (f32x4){0.f, 0.f, 0.f, 0.f};

    // Staging: 1024 chunks of 16B per tile; chunk c = t*256 + tid.
    // row r = c>>3 (8 chunks per 64-elem row), chunk-in-row cc = c&7.
    const unsigned short* aSrc[4];
    const unsigned short* bSrc[4];
    unsigned short* aDst[4];
    unsigned short* bDst[4];
#pragma unroll
    for (int t = 0; t < 4; t++) {
        int c  = t * 256 + tid;
        int r  = c >> 3;
        int cc = c & 7;
        aSrc[t] = Ab + (size_t)(m0 + r) * K_TOT + cc * 8;
        bSrc[t] = Wb + (size_t)(n0 + r) * K_TOT + cc * 8;
        aDst[t] = &sA[c * 8];
        bDst[t] = &sB[c * 8];
    }

    // LDS read bases: lane holds row (lane&15) of its fragment, k = (lane>>4)*8.
    const int aBase = (wr * 64 + (lane & 15)) * BK + ((lane >> 4) << 3);
    const int bBase = (wc * 64 + (lane & 15)) * BK + ((lane >> 4) << 3);

    for (int kt = 0; kt < K_TOT / BK; ++kt) {
        if (kt) __syncthreads();   // previous compute must finish before overwrite
#pragma unroll
        for (int t = 0; t < 4; t++) {
            gld_lds16(aSrc[t] + kt * BK, aDst[t]);
            gld_lds16(bSrc[t] + kt * BK, bDst[t]);
        }
        __syncthreads();           // compiler emits vmcnt(0) drain before barrier

#pragma unroll
        for (int kk = 0; kk < 2; kk++) {
            bf16x8 af[4], bf[4];
#pragma unroll
            for (int i = 0; i < 4; i++)
                af[i] = *reinterpret_cast<const bf16x8*>(&sA[aBase + i * 16 * BK + kk * 32]);
#pragma unroll
            for (int j = 0; j < 4; j++)
                bf[j] = *reinterpret_cast<const bf16x8*>(&sB[bBase + j * 16 * BK + kk * 32]);
#pragma unroll
            for (int i = 0; i < 4; i++)
#pragma unroll
                for (int j = 0; j < 4; j++)
                    acc[i][j] = __builtin_amdgcn_mfma_f32_16x16x32_bf16(
                        af[i], bf[j], acc[i][j], 0, 0, 0);
        }
    }

    // Epilogue: C/D layout (m89-verified): col = lane&15, row = (lane>>4)*4 + reg.
    // n-tile (128 wide) is always inside one of q/k/v since 768 % 128 == 0.
    const int which = n0 / H;
    const int c0    = n0 - which * H;
    float* outBase  = out + (size_t)which * OUT_PER;

#pragma unroll
    for (int j = 0; j < 4; j++) {
        const int nl  = wc * 64 + j * 16 + (lane & 15);
        const float bv = bias[n0 + nl];
        const int col  = c0 + nl;
#pragma unroll
        for (int i = 0; i < 4; i++) {
            const int mrow = m0 + wr * 64 + i * 16 + ((lane >> 4) << 2);
#pragma unroll
            for (int r = 0; r < 4; r++) {
                outBase[(size_t)(mrow + r) * H + col] = acc[i][j][r] + bv;
            }
        }
    }
}

extern "C" void kernel_launch(void* const* d_in, const int* in_sizes, int n_in,
                              void* d_out, int out_size, void* d_ws, size_t ws_size,
                              hipStream_t stream) {
    const float* hs = (const float*)d_in[0];
    const float* wq = (const float*)d_in[1];
    const float* bq = (const float*)d_in[2];
    const float* wk = (const float*)d_in[3];
    const float* bk = (const float*)d_in[4];
    const float* wv = (const float*)d_in[5];
    const float* bv = (const float*)d_in[6];

    unsigned short* Ab = (unsigned short*)d_ws;                      // 50,331,648 B
    unsigned short* Wb = Ab + (size_t)M_TOT * K_TOT;                 //  3,538,944 B
    float* biasb       = (float*)(Wb + (size_t)N_TOT * K_TOT);       //      9,216 B

    hipLaunchKernelGGL(convert_pack, dim3(2048), dim3(256), 0, stream,
                       hs, wq, wk, wv, bq, bk, bv, Ab, Wb, biasb);

    hipLaunchKernelGGL(qkv_gemm, dim3((M_TOT / BM) * NB_N), dim3(256), 0, stream,
                       Ab, Wb, biasb, (float*)d_out);
}